// Round 2
// 1981.525 us; speedup vs baseline: 2.7339x; 2.7339x over previous
//
#include <hip/hip_runtime.h>
#include <math.h>

// ---------------------------------------------------------------------------
// WhereValuePredictor on MI355X — round 7 (resubmit; r1 bench was an infra
// GPUAcquisitionTimeout, no counters): batched h-exchange via LDS staging.
// r6 counters: lstm_seq (question) = 1975us/launch = 15.4us/step with
// VALUBusy 0.9%, VGPR=60. Diagnosis: the per-lane u[32] agent-scope atomic
// loads were NOT kept in flight (u[32] alone needs 64 VGPRs > the 60
// allocated) -> each dependent MFMA waited ~550-900cy on the coherence
// point, ~32-64 serialized IC latencies/step ~= 14.7us ~= measured.
// Fix: cooperative batched stage of the full h slab (NT*16 rows x 512
// units) into LDS hR[][520] (padded stride vs bank pathology): 2*NT
// independent 16B loads/thread issued unrolled -> ~1 IC latency total;
// MFMA B-fragments then come from ds_read_b128. Everything else unchanged.
// ---------------------------------------------------------------------------

using f32x4 = __attribute__((ext_vector_type(4))) float;
using s16x8 = __attribute__((ext_vector_type(8))) short;
typedef unsigned long long ulong_t;

#define ASYNC_COPY16(gsrc, ldst)                                               \
  __builtin_amdgcn_global_load_lds(                                            \
      (const __attribute__((address_space(1))) void*)(gsrc),                   \
      (__attribute__((address_space(3))) void*)(ldst), 16, 0, 0)

static __device__ __forceinline__ float sigm(float x) {
  return 1.0f / (1.0f + expf(-x));
}

static __device__ __forceinline__ unsigned short f2b_one(float x) {
  unsigned int u = __float_as_uint(x);
  u = (u + 0x7FFFu + ((u >> 16) & 1u)) >> 16;  // RNE
  return (unsigned short)u;
}

// ------------------------- fp32 -> bf16 convert ----------------------------
__global__ __launch_bounds__(256) void f2b_kernel(
    const float* __restrict__ in, unsigned short* __restrict__ out, int n4)
{
  const int i = blockIdx.x * 256 + threadIdx.x;
  if (i >= n4) return;
  const float4 v = ((const float4*)in)[i];
  ushort4 r;
  r.x = f2b_one(v.x); r.y = f2b_one(v.y);
  r.z = f2b_one(v.z); r.w = f2b_one(v.w);
  ((ushort4*)out)[i] = r;
}

// ------------------------- masks -------------------------------------------
__global__ __launch_bounds__(256) void mask_kernel(
    const float* __restrict__ qe, const float* __restrict__ pce,
    float* __restrict__ qmask, float* __restrict__ cmask)
{
  const int w = threadIdx.x >> 6;
  const int lane = threadIdx.x & 63;
  const int row = blockIdx.x * 4 + w;  // 0..9215
  const float* src = (row < 4096) ? (qe + (size_t)row * 1024)
                                  : (pce + (size_t)(row - 4096) * 1024);
  float s = 0.f;
#pragma unroll
  for (int j = 0; j < 16; ++j) s += fabsf(src[lane + j * 64]);
#pragma unroll
  for (int off = 32; off > 0; off >>= 1) s += __shfl_down(s, off, 64);
  if (lane == 0) {
    const float m = (s != 0.f) ? 1.f : 0.f;
    if (row < 4096) qmask[row] = m;
    else cmask[row - 4096] = m;
  }
}

// ------------------------- bf16 MFMA GEMM (m97-style) ----------------------
__global__ __launch_bounds__(256) void mfma_gemm_kernel(
    const unsigned short* __restrict__ X, const unsigned short* __restrict__ W,
    const float* __restrict__ bias, float* __restrict__ C,
    int K, int ldx, int ldw, int k0w, int ldc, int c0)
{
  __shared__ unsigned short As[128 * 32];
  __shared__ unsigned short Bs[128 * 32];
  const int tid = threadIdx.x;
  const int w = tid >> 6;
  const int l = tid & 63;
  const int m0 = blockIdx.y * 128;
  const int n0 = blockIdx.x * 128;
  const int wm = (w >> 1) * 64;
  const int wn = (w & 1) * 64;

  const unsigned short* xg =
      X + (size_t)(m0 + w * 32 + (l >> 2)) * ldx + (l & 3) * 8;
  const unsigned short* wgp =
      W + (size_t)(n0 + w * 32 + (l >> 2)) * ldw + k0w + (l & 3) * 8;
  unsigned short* asb = As + w * 1024;
  unsigned short* bsb = Bs + w * 1024;

  const int fr = l & 15;
  const int fq = l >> 4;
  const unsigned short* aRd = As + (wm + fr) * 32 + fq * 8;
  const unsigned short* bRd = Bs + (wn + fr) * 32 + fq * 8;

  f32x4 acc[4][4];
#pragma unroll
  for (int i = 0; i < 4; ++i)
#pragma unroll
    for (int j = 0; j < 4; ++j) acc[i][j] = (f32x4){0.f, 0.f, 0.f, 0.f};

  for (int k0 = 0; k0 < K; k0 += 32) {
    ASYNC_COPY16(xg + k0, asb);
    ASYNC_COPY16(xg + (size_t)16 * ldx + k0, asb + 512);
    ASYNC_COPY16(wgp + k0, bsb);
    ASYNC_COPY16(wgp + (size_t)16 * ldw + k0, bsb + 512);
    __syncthreads();
    s16x8 a[4], b[4];
#pragma unroll
    for (int i = 0; i < 4; ++i) a[i] = *(const s16x8*)(aRd + i * 512);
#pragma unroll
    for (int j = 0; j < 4; ++j) b[j] = *(const s16x8*)(bRd + j * 512);
#pragma unroll
    for (int i = 0; i < 4; ++i)
#pragma unroll
      for (int j = 0; j < 4; ++j)
        acc[i][j] = __builtin_amdgcn_mfma_f32_16x16x32_bf16(
            a[i], b[j], acc[i][j], 0, 0, 0);
    __syncthreads();
  }

#pragma unroll
  for (int j = 0; j < 4; ++j) {
    const int col = n0 + wn + j * 16 + fr;
    const float bj = bias ? bias[col] : 0.f;
#pragma unroll
    for (int i = 0; i < 4; ++i) {
      const int row = m0 + wm + i * 16 + fq * 4;
#pragma unroll
      for (int r = 0; r < 4; ++r)
        C[(size_t)(row + r) * ldc + c0 + col] = acc[i][j][r] + bj;
    }
  }
}

// ------------------------- generic fp32 GEMM (small tails) ------------------
__global__ __launch_bounds__(256) void gemm_kernel(
    const float* __restrict__ X, const float* __restrict__ W,
    const float* __restrict__ bias, float* __restrict__ C,
    int M, int N, int K, int ldx, int ldw, int k0w, int ldc, int c0)
{
  __shared__ float Xs[16][68];
  __shared__ float Ws[16][68];
  const int tid = threadIdx.x;
  const int m0 = blockIdx.y * 64;
  const int n0 = blockIdx.x * 64;
  const int lrow = tid >> 2;
  const int lkk = (tid & 3) << 2;
  const float* Xp = X + (size_t)(m0 + lrow) * ldx + lkk;
  const float* Wp = W + (size_t)(n0 + lrow) * ldw + k0w + lkk;
  const int tm = (tid >> 4) << 2;
  const int tn = (tid & 15) << 2;
  float acc[4][4];
#pragma unroll
  for (int i = 0; i < 4; ++i)
#pragma unroll
    for (int j = 0; j < 4; ++j) acc[i][j] = 0.f;

  for (int k0 = 0; k0 < K; k0 += 16) {
    const float4 xv = *(const float4*)(Xp + k0);
    const float4 wv = *(const float4*)(Wp + k0);
    Xs[lkk + 0][lrow] = xv.x; Xs[lkk + 1][lrow] = xv.y;
    Xs[lkk + 2][lrow] = xv.z; Xs[lkk + 3][lrow] = xv.w;
    Ws[lkk + 0][lrow] = wv.x; Ws[lkk + 1][lrow] = wv.y;
    Ws[lkk + 2][lrow] = wv.z; Ws[lkk + 3][lrow] = wv.w;
    __syncthreads();
#pragma unroll
    for (int kk = 0; kk < 16; ++kk) {
      const float4 a4 = *(const float4*)&Xs[kk][tm];
      const float4 b4 = *(const float4*)&Ws[kk][tn];
      const float av[4] = {a4.x, a4.y, a4.z, a4.w};
      const float bv[4] = {b4.x, b4.y, b4.z, b4.w};
#pragma unroll
      for (int i = 0; i < 4; ++i)
#pragma unroll
        for (int j = 0; j < 4; ++j) acc[i][j] += av[i] * bv[j];
    }
    __syncthreads();
  }
  float bvv[4] = {0.f, 0.f, 0.f, 0.f};
  if (bias) {
#pragma unroll
    for (int j = 0; j < 4; ++j) bvv[j] = bias[n0 + tn + j];
  }
#pragma unroll
  for (int i = 0; i < 4; ++i)
#pragma unroll
    for (int j = 0; j < 4; ++j)
      C[(size_t)(m0 + tm + i) * ldc + c0 + n0 + tn + j] = acc[i][j] + bvv[j];
}

// ------------------------- persistent LSTM scan (fence-free) ----------------
// Grid (32, BG): blockIdx.x = dir*16 + unit-slice w (32 units, 8 waves x 4).
// blockIdx.y = batch group (NT 16-row tiles). All cross-WG traffic is
// agent-scope relaxed atomics -> no threadfence / L2 maintenance. Per step:
//   C: cooperative BATCHED stage of h slab (NT*16 x 512 bf16) -> hR in LDS
//      (2*NT independent 16B loads per thread, all in flight -> 1 latency)
//   D: MFMA gates (B-frags via ds_read_b128 from hR) + preS -> update -> hS
//   E: syncthreads; cooperative h atomic stores; (out written in D)
//   G: syncthreads (drains stores); tid0 arrives (fire-and-forget) + spins
//      on its (dir,bg) counter while all threads prefetch next pre -> preS.
template <int NT>
__global__ __launch_bounds__(512, 2) void lstm_seq_kernel(
    const float* __restrict__ pre,           // [Bn][T][4096]
    const unsigned short* __restrict__ whh,  // bf16 [2 dirs][2048][512]
    unsigned short* __restrict__ hbuf,       // bf16 [2 slots][640][512]
    float* __restrict__ out,                 // [Bn][T][1024]
    int T, unsigned* __restrict__ bar, unsigned base)
{
  __shared__ float preS[NT][4][16][34];      // [nt][gate][n][unit+pad]
  __shared__ float Tr[8][4][4][16];          // [wave][gate][du][n] wave-local
  __shared__ unsigned short hS[NT * 16][36]; // [n_local][unit+pad] (write stg)
  __shared__ unsigned short hR[NT * 16][520];// [n_local][unit] staged h read
  const int tid = threadIdx.x;               // 0..511
  const int v = tid >> 6;                    // wave 0..7
  const int l = tid & 63;
  const int d = blockIdx.x >> 4;
  const int w = blockIdx.x & 15;             // slice: units w*32..+31
  const int bg = blockIdx.y;
  const int fr = l & 15;
  const int fq = l >> 4;
  const int ubase = w * 32;
  const int unit = ubase + v * 4 + fq;
  const int nbase = bg * (NT * 16);
  const size_t SLOT = (size_t)640 * 512;
  unsigned* ctr = bar + (d * 8 + bg) * 16;   // 64B-spaced counters

  // A-frags: MFMA A row m=fr -> whh row (m>>2)*512 + ubase + v*4 + (m&3)
  s16x8 afr[16];
  {
    const unsigned short* arow = whh + (size_t)d * 2048 * 512 +
        ((size_t)(fr >> 2) * 512 + ubase + v * 4 + (fr & 3)) * 512 + fq * 8;
#pragma unroll
    for (int kk = 0; kk < 16; ++kk)
      afr[kk] = *(const s16x8*)(arow + kk * 32);
  }

  float creg[NT];
#pragma unroll
  for (int i = 0; i < NT; ++i) creg[i] = 0.f;

  // staging thread mapping: one float4 per thread per nt
  const int sc = tid & 7;
  const int sn = (tid >> 3) & 15;
  const int sg = tid >> 7;

  {  // prologue: stage pre for t=0
    const int tt0 = d ? (T - 1) : 0;
#pragma unroll
    for (int nt = 0; nt < NT; ++nt) {
      const int n = nbase + nt * 16 + sn;
      const float4 pv = *(const float4*)(
          pre + ((size_t)n * T + tt0) * 4096 + d * 2048 + sg * 512 + ubase +
          sc * 4);
      *(float4*)&preS[nt][sg][sn][sc * 4] = pv;
    }
  }
  __syncthreads();

  for (int t = 0; t < T; ++t) {
    const int tt = d ? (T - 1 - t) : t;
    const unsigned short* hr = hbuf + (size_t)((t + 1) & 1) * SLOT;
    unsigned short* hw = hbuf + (size_t)(t & 1) * SLOT;

    // ---- C: batched cooperative h slab load -> hR (one IC latency) ----
    if (t > 0) {
      ulong_t u0[2 * NT], u1[2 * NT];
      const ulong_t* hq = (const ulong_t*)hr + (size_t)nbase * 128;
#pragma unroll
      for (int i = 0; i < 2 * NT; ++i) {
        const int cid = i * 512 + tid;                 // 16B chunk id
        const ulong_t* p = hq + (size_t)(cid >> 6) * 128 + (cid & 63) * 2;
        u0[i] = __hip_atomic_load(p, __ATOMIC_RELAXED,
                                  __HIP_MEMORY_SCOPE_AGENT);
        u1[i] = __hip_atomic_load(p + 1, __ATOMIC_RELAXED,
                                  __HIP_MEMORY_SCOPE_AGENT);
      }
#pragma unroll
      for (int i = 0; i < 2 * NT; ++i) {
        const int cid = i * 512 + tid;
        ulong_t* dst = (ulong_t*)&hR[cid >> 6][(cid & 63) * 8];
        dst[0] = u0[i];
        dst[1] = u1[i];
      }
    }
    __syncthreads();  // hR ready (no-op consumption at t==0)

    // ---- D: gates + state update ----
#pragma unroll
    for (int nt = 0; nt < NT; ++nt) {
      f32x4 acc = (f32x4){0.f, 0.f, 0.f, 0.f};
      if (t > 0) {
        const unsigned short* bRd = &hR[nt * 16 + fr][fq * 8];
#pragma unroll
        for (int kk = 0; kk < 16; ++kk) {
          const s16x8 bv = *(const s16x8*)(bRd + kk * 32);
          acc = __builtin_amdgcn_mfma_f32_16x16x32_bf16(afr[kk], bv, acc,
                                                        0, 0, 0);
        }
      }
      // wave-local transpose (C row fq*4+r -> gate fq, du r; col fr -> n)
#pragma unroll
      for (int r = 0; r < 4; ++r) Tr[v][fq][r][fr] = acc[r];
      const int uu = v * 4 + fq;
      const float gi = Tr[v][0][fq][fr] + preS[nt][0][fr][uu];
      const float gf = Tr[v][1][fq][fr] + preS[nt][1][fr][uu];
      const float gg = Tr[v][2][fq][fr] + preS[nt][2][fr][uu];
      const float go = Tr[v][3][fq][fr] + preS[nt][3][fr][uu];
      const float cn = sigm(gf) * creg[nt] + sigm(gi) * tanhf(gg);
      const float hn = sigm(go) * tanhf(cn);
      creg[nt] = cn;
      hS[nt * 16 + fr][uu] = f2b_one(hn);
      const int n = nbase + nt * 16 + fr;
      out[((size_t)n * T + tt) * 1024 + d * 512 + unit] = hn;
    }
    __syncthreads();  // hS complete; preS fully consumed; hR consumed

    // ---- E: cooperative h store (agent atomics) ----
    {
      const int un = tid & 7;       // ulong within 32-unit slice
      const int nl = tid >> 3;      // 0..63
      for (int p = nl; p < NT * 16; p += 64) {
        const ulong_t val = *(const ulong_t*)&hS[p][un * 4];
        __hip_atomic_store(
            (ulong_t*)(hw + (size_t)(nbase + p) * 512 + ubase) + un, val,
            __ATOMIC_RELAXED, __HIP_MEMORY_SCOPE_AGENT);
      }
    }
    __syncthreads();  // drains h stores (vmcnt) for ALL threads

    // ---- G: arrive (non-blocking), prefetch in the spin shadow, wait ----
    if (tid == 0)
      __hip_atomic_fetch_add(ctr, 1u, __ATOMIC_RELAXED,
                             __HIP_MEMORY_SCOPE_AGENT);
    if (t + 1 < T) {
      const int ttn = d ? (T - 2 - t) : (t + 1);
      float4 pv[NT];
#pragma unroll
      for (int nt = 0; nt < NT; ++nt) {
        const int n = nbase + nt * 16 + sn;
        pv[nt] = *(const float4*)(
            pre + ((size_t)n * T + ttn) * 4096 + d * 2048 + sg * 512 + ubase +
            sc * 4);
      }
#pragma unroll
      for (int nt = 0; nt < NT; ++nt)
        *(float4*)&preS[nt][sg][sn][sc * 4] = pv[nt];
      if (tid == 0) {
        const unsigned target = base + (unsigned)(t + 1) * 16u;
        long spins = 0;
        while (__hip_atomic_load(ctr, __ATOMIC_RELAXED,
                                 __HIP_MEMORY_SCOPE_AGENT) < target) {
          __builtin_amdgcn_s_sleep(2);
          if (++spins > 2000000L) break;  // safety valve
        }
      }
    }
    __syncthreads();
  }
}

// ------------------------- column attention pool ----------------------------
__global__ __launch_bounds__(256) void colpool_kernel(
    const float* __restrict__ cenc, const float* __restrict__ caw,
    const float* __restrict__ cab, const float* __restrict__ cmask,
    float* __restrict__ colh)
{
  __shared__ float part[8][33];
  __shared__ float wbuf[8];
  const int p = blockIdx.x;
  const int t = threadIdx.x >> 5;
  const int ln = threadIdx.x & 31;
  const float* row = cenc + ((size_t)p * 8 + t) * 1024;
  float s = 0.f;
  for (int j = ln; j < 1024; j += 32) s += row[j] * caw[j];
  part[t][ln] = s;
  __syncthreads();
  if (threadIdx.x < 8) {
    float lg = 0.f;
    for (int i = 0; i < 32; ++i) lg += part[threadIdx.x][i];
    lg += cab[0];
    wbuf[threadIdx.x] = (cmask[p * 8 + threadIdx.x] > 0.f) ? lg : -INFINITY;
  }
  __syncthreads();
  if (threadIdx.x == 0) {
    float mx = -INFINITY;
    for (int i = 0; i < 8; ++i) mx = fmaxf(mx, wbuf[i]);
    float e[8];
    float sum = 0.f;
    for (int i = 0; i < 8; ++i) { e[i] = expf(wbuf[i] - mx); sum += e[i]; }
    for (int i = 0; i < 8; ++i) wbuf[i] = e[i] / sum;
  }
  __syncthreads();
  for (int h = threadIdx.x; h < 1024; h += 256) {
    float a = 0.f;
#pragma unroll
    for (int i = 0; i < 8; ++i) a += wbuf[i] * cenc[((size_t)p * 8 + i) * 1024 + h];
    colh[(size_t)p * 1024 + h] = a;
  }
}

// ------------------------- gather observed ----------------------------------
__global__ __launch_bounds__(256) void gather_kernel(
    const float* __restrict__ colh, const int* __restrict__ gold_num,
    const int* __restrict__ gold_cols, const int* __restrict__ ncol,
    float* __restrict__ obs)
{
  const int idx = blockIdx.x * 256 + threadIdx.x;
  const int h = idx & 1023;
  const int k = (idx >> 10) & 3;
  const int b = idx >> 12;
  int gn = gold_num[b];
  if (gn > 4) gn = 4;
  const float m = (k < gn) ? 1.f : 0.f;
  const int col = gold_cols[b * 4 + k];
  const int NC = ncol[0];
  obs[idx] = m * colh[(size_t)(b * NC + col) * 1024 + h];
}

// ------------------------- fused attention (per b,k) ------------------------
__global__ __launch_bounds__(128) void attn_kernel(
    const float* __restrict__ akey, const float* __restrict__ qenc,
    const float* __restrict__ qmask, float* __restrict__ qhid)
{
  __shared__ float ak[1024];
  __shared__ float red[128];
  __shared__ float at[128];
  const int bk = blockIdx.x;
  const int b = bk >> 2;
  const int tid = threadIdx.x;
  for (int i = tid; i < 1024; i += 128) ak[i] = akey[(size_t)bk * 1024 + i];
  __syncthreads();
  const float* qrow = qenc + ((size_t)b * 128 + tid) * 1024;
  float s = 0.f;
  for (int hh = 0; hh < 1024; hh += 4) {
    const float4 qv = *(const float4*)(qrow + hh);
    s += ak[hh] * qv.x + ak[hh + 1] * qv.y + ak[hh + 2] * qv.z + ak[hh + 3] * qv.w;
  }
  s = (qmask[b * 128 + tid] > 0.f) ? s : -INFINITY;
  at[tid] = s;
  red[tid] = s;
  __syncthreads();
  for (int off = 64; off > 0; off >>= 1) {
    if (tid < off) red[tid] = fmaxf(red[tid], red[tid + off]);
    __syncthreads();
  }
  const float mx = red[0];
  __syncthreads();
  const float e = expf(at[tid] - mx);
  red[tid] = e;
  __syncthreads();
  for (int off = 64; off > 0; off >>= 1) {
    if (tid < off) red[tid] += red[tid + off];
    __syncthreads();
  }
  const float inv = 1.f / red[0];
  __syncthreads();
  at[tid] = e * inv;
  __syncthreads();
  for (int h = tid; h < 1024; h += 128) {
    float a = 0.f;
    for (int q = 0; q < 128; ++q)
      a += at[q] * qenc[((size_t)b * 128 + q) * 1024 + h];
    qhid[(size_t)bk * 1024 + h] = a;
  }
}

// ------------------------- final epilogue -----------------------------------
__global__ __launch_bounds__(64) void final_kernel(
    const float* __restrict__ A, const float* __restrict__ Bm,
    const float* __restrict__ w2, const float* __restrict__ b2,
    const int* __restrict__ gold_num, const float* __restrict__ qmask,
    float* __restrict__ out)
{
  const int bkq = blockIdx.x;
  const int q = bkq & 127;
  const int k = (bkq >> 7) & 3;
  const int b = bkq >> 9;
  int gn = gold_num[b];
  if (gn > 4) gn = 4;
  const bool act = (k < gn) && (qmask[b * 128 + q] > 0.f);
  const int lane = threadIdx.x;
  const int obase = (b * 4 + k) * 128 + q;
  if (!act) {
    if (lane == 0) {
      out[obase] = -1e30f;          // finite sentinel (ref has -inf; see r1)
      out[16384 + obase] = -1e30f;
    }
    return;
  }
  const float* Ar = A + ((size_t)b * 128 + q) * 1024;
  const float* Br = Bm + (size_t)(b * 4 + k) * 1024;
  float s0 = 0.f, s1 = 0.f;
  for (int o = lane; o < 1024; o += 64) {
    const float v = tanhf(Ar[o] + Br[o]);
    s0 += v * w2[o];
    s1 += v * w2[1024 + o];
  }
#pragma unroll
  for (int off = 32; off > 0; off >>= 1) {
    s0 += __shfl_down(s0, off, 64);
    s1 += __shfl_down(s1, off, 64);
  }
  if (lane == 0) {
    out[obase] = s0 + b2[0];
    out[16384 + obase] = s1 + b2[1];
  }
}

// ---------------------------------------------------------------------------
extern "C" void kernel_launch(void* const* d_in, const int* in_sizes, int n_in,
                              void* d_out, int out_size, void* d_ws, size_t ws_size,
                              hipStream_t stream)
{
  const float* qe      = (const float*)d_in[0];
  const float* pce     = (const float*)d_in[1];
  const int* gold_num  = (const int*)d_in[2];
  const int* gold_cols = (const int*)d_in[3];
  const int* ncol      = (const int*)d_in[5];
  const float* q_Wih   = (const float*)d_in[6];
  const float* q_Whh   = (const float*)d_in[7];
  const float* q_b     = (const float*)d_in[8];
  const float* c_Wih   = (const float*)d_in[9];
  const float* c_Whh   = (const float*)d_in[10];
  const float* c_b     = (const float*)d_in[11];
  const float* caw     = (const float*)d_in[12];
  const float* cab     = (const float*)d_in[13];
  const float* obaW    = (const float*)d_in[14];
  const float* obab    = (const float*)d_in[15];
  const float* obcW    = (const float*)d_in[16];
  const float* obcb    = (const float*)d_in[17];
  const float* qpW     = (const float*)d_in[18];
  const float* qpb     = (const float*)d_in[19];
  const float* o1W     = (const float*)d_in[20];
  const float* o1b     = (const float*)d_in[21];
  const float* o2W     = (const float*)d_in[22];
  const float* o2b     = (const float*)d_in[23];
  float* outp = (float*)d_out;

  float* ws = (float*)d_ws;
  size_t off = 0;
  float* pre  = ws + off; off += 640UL * 8 * 4096;   // also reused as A matrix
  float* bufA = ws + off; off += 640UL * 8 * 1024;
  float* bufB = ws + off; off += 640UL * 8 * 1024;
  float* colh = ws + off; off += 640UL * 1024;
  float* qmask = ws + off; off += 4096;
  float* cmask = ws + off; off += 5120;
  float* obs  = ws + off; off += 131072;
  float* akey = ws + off; off += 131072;
  float* qhid = ws + off; off += 131072;
  float* vec  = ws + off; off += 262144;
  float* Bm   = ws + off; off += 131072;
  unsigned short* xb = (unsigned short*)(ws + off); off += 2621440;  // bf16 acts
  unsigned short* wb = (unsigned short*)(ws + off); off += 2097152;  // bf16 Wih
  unsigned short* whhq = (unsigned short*)(ws + off); off += 2097152; // q_Whh bf16
  unsigned short* whhc = (unsigned short*)(ws + off); off += 2097152; // c_Whh bf16
  unsigned short* hbuf = (unsigned short*)(ws + off); off += 327680;  // 2 slots
  unsigned* bar = (unsigned*)(ws + off); off += 256;  // 16 counters x 64B
  float* Amat = pre;

  const dim3 blk(256);
  auto cvt = [&](const float* src, unsigned short* dst, int n) {
    hipLaunchKernelGGL(f2b_kernel, dim3((n / 4 + 255) / 256), blk, 0, stream,
                       src, dst, n / 4);
  };

  // counters must start at 0 every call (ws is poisoned 0xAA)
  hipMemsetAsync(bar, 0, 1024, stream);

  hipLaunchKernelGGL(mask_kernel, dim3(2304), blk, 0, stream, qe, pce, qmask, cmask);

  // recurrent weights -> bf16 (once)
  cvt(q_Whh, whhq, 4194304);
  cvt(c_Whh, whhc, 4194304);

  // ---- column biLSTM (B=640, T=8): grid (32,8), NT=5 ----
  // counters 0..15 (dir*8+bg), 16 arrivals each; +128/launch
  for (int l = 0; l < 2; ++l) {
    const float* xin = (l == 0) ? pce : bufA;
    float* enc = (l == 0) ? bufA : bufB;
    cvt(xin, xb, 5242880);
    cvt(c_Wih + (size_t)l * 4194304, wb, 4194304);
    hipLaunchKernelGGL(mfma_gemm_kernel, dim3(4096 / 128, 5120 / 128), blk, 0,
                       stream, xb, wb, c_b + l * 4096, pre,
                       1024, 1024, 1024, 0, 4096, 0);
    hipLaunchKernelGGL((lstm_seq_kernel<5>), dim3(32, 8), dim3(512), 0, stream,
                       pre, whhc + (size_t)l * 2 * 2048 * 512, hbuf, enc,
                       8, bar, (unsigned)(l * 128));
  }
  hipLaunchKernelGGL(colpool_kernel, dim3(640), blk, 0, stream,
                     bufB, caw, cab, cmask, colh);
  hipLaunchKernelGGL(gather_kernel, dim3(512), blk, 0, stream,
                     colh, gold_num, gold_cols, ncol, obs);

  // ---- question biLSTM (B=32, T=128): grid (32,1), NT=2 ----
  // counters {0,8} start at 256; +2048/launch
  for (int l = 0; l < 2; ++l) {
    const float* xin = (l == 0) ? qe : bufA;
    float* enc = (l == 0) ? bufA : bufB;
    cvt(xin, xb, 4194304);
    cvt(q_Wih + (size_t)l * 4194304, wb, 4194304);
    hipLaunchKernelGGL(mfma_gemm_kernel, dim3(4096 / 128, 4096 / 128), blk, 0,
                       stream, xb, wb, q_b + l * 4096, pre,
                       1024, 1024, 1024, 0, 4096, 0);
    hipLaunchKernelGGL((lstm_seq_kernel<2>), dim3(32, 1), dim3(512), 0, stream,
                       pre, whhq + (size_t)l * 2 * 2048 * 512, hbuf, enc,
                       128, bar, (unsigned)(256 + l * 2048));
  }
  const float* qenc = bufB;

  // att_key = observed @ ob_attn_W^T + b   (small, fp32 path)
  hipLaunchKernelGGL(gemm_kernel, dim3(16, 2), blk, 0, stream,
                     obs, obaW, obab, akey, 128, 1024, 1024, 1024, 1024, 0, 1024, 0);
  hipLaunchKernelGGL(attn_kernel, dim3(128), dim3(128), 0, stream,
                     akey, qenc, qmask, qhid);
  hipLaunchKernelGGL(gemm_kernel, dim3(16, 2), blk, 0, stream,
                     obs, obcW, obcb, vec, 128, 1024, 1024, 1024, 1024, 0, 2048, 0);
  hipLaunchKernelGGL(gemm_kernel, dim3(16, 2), blk, 0, stream,
                     qhid, qpW, qpb, vec, 128, 1024, 1024, 1024, 1024, 0, 2048, 1024);
  // A = qenc @ out1_W[:, :1024]^T + b1  (bf16 MFMA)
  cvt(qenc, xb, 4194304);
  cvt(o1W, wb, 3145728);
  hipLaunchKernelGGL(mfma_gemm_kernel, dim3(1024 / 128, 4096 / 128), blk, 0,
                     stream, xb, wb, o1b, Amat, 1024, 1024, 3072, 0, 1024, 0);
  // Bm = vec @ out1_W[:, 1024:]^T (fp32 path)
  hipLaunchKernelGGL(gemm_kernel, dim3(16, 2), blk, 0, stream,
                     vec, o1W, nullptr, Bm, 128, 1024, 2048, 2048, 3072, 1024, 1024, 0);
  hipLaunchKernelGGL(final_kernel, dim3(16384), dim3(64), 0, stream,
                     Amat, Bm, o2W, o2b, gold_num, qmask, outp);
}